// Round 8
// baseline (3605.194 us; speedup 1.0000x reference)
//
#include <hip/hip_runtime.h>

#define SEQ_L 1000
#define HID   51
#define NB    4      // batch elements per block; grid = 1024/4 = 256 = 1 block/CU
#define NTH   768    // 12 waves: waves 0-3 R1-rows, 4-7 W2-rows, 8-11 R2-rows

__device__ __forceinline__ float sigmoid_f(float x) {
    return 1.0f / (1.0f + __expf(-x));
}

// Two-cell pipelined LSTM, 1-step skew, role-split matvecs so each thread
// holds only 51 weight floats (spill-proof; round-5 showed the allocator
// spills rather than exceed 128 VGPRs).
//   X: role0 gates1(i)+act->g1a | role1 W2*h1(i-1)->regs | role2 R2*h2(i-2)->pr2
//   M: role1 finish gates2(i-1)->g2a | role0-wave-g update1(i)->h1s
//   Y: role2-wave-g update2(i-1)->h2s + output projection
__global__ __launch_bounds__(NTH, 3)
void lstm2_kernel(const float* __restrict__ input,
                  const float* __restrict__ W1, const float* __restrict__ b1,
                  const float* __restrict__ R1, const float* __restrict__ W2,
                  const float* __restrict__ b2, const float* __restrict__ R2,
                  const float* __restrict__ w_out, const float* __restrict__ b_out,
                  float* __restrict__ out)
{
    const int tid  = threadIdx.x;
    const int n0   = blockIdx.x * NB;
    const int wave = tid >> 6;
    const int l    = tid & 63;
    const int role = wave >> 2;      // 0: R1 (cell1), 1: W2, 2: R2
    const int g    = wave & 3;       // gate index (X/M); batch column (updates)
    const bool act = (l < HID);
    const int  r   = g * HID + l;    // gate row

    __shared__ float4 h1s[HID];          // h1 state, [hid] x 4 batches
    __shared__ float4 h2s[HID];          // h2 state
    __shared__ float4 pr2[4 * HID];      // R2*h2 partials, [row] x 4 batches
    __shared__ float  g1a[NB][4 * HID];  // activated gates cell 1
    __shared__ float  g2a[NB][4 * HID];  // activated gates cell 2
    __shared__ float  xs[NB][SEQ_L + 1]; // staged input (+1 zero pad for i==L)

    // stage input (coalesced along L)
    for (int idx = tid; idx < NB * (SEQ_L + 1); idx += NTH) {
        int b = idx / (SEQ_L + 1);
        int t = idx - b * (SEQ_L + 1);
        xs[b][t] = (t < SEQ_L) ? input[(n0 + b) * SEQ_L + t] : 0.f;
    }
    if (tid < HID) {
        h1s[tid] = float4{0.f, 0.f, 0.f, 0.f};
        h2s[tid] = float4{0.f, 0.f, 0.f, 0.f};
    }

    // ---- per-role weight row in VGPRs (51 floats, fully unrolled -> static)
    const float* Wm = (role == 0) ? R1 : (role == 1) ? W2 : R2;
    float wt[HID];
    float w1r = 0.f, bias = 0.f;
    if (act) {
        #pragma unroll
        for (int j = 0; j < HID; ++j) wt[j] = Wm[r * HID + j];
        if (role == 0)      { w1r = W1[r]; bias = b1[r]; }
        else if (role == 1) { bias = b2[r]; }
    }
    const bool is_cand = (g == 2);          // wave-uniform tanh-gate flag
    const float sc = is_cand ? 2.f : 1.f;   // tanh(x) = 2*sigmoid(2x)-1

    float c1 = 0.f, c2 = 0.f;   // c1 lives in role0 (batch g, hid l); c2 in role2
    const float woutr = act ? w_out[l] : 0.f;
    const float bout  = b_out[0];
    float* h1p = (float*)h1s;
    float* h2p = (float*)h2s;

    float dW0 = 0.f, dW1 = 0.f, dW2 = 0.f, dW3 = 0.f;  // role1 partial across bar1

    __syncthreads();

    for (int i = 0; i <= SEQ_L; ++i) {   // i: cell-1 time; i-1: cell-2 time
        const int t2 = i - 1;
        // ---------- phase X: the three matvecs ----------
        if (act) {
            float a0, a1, a2, a3;
            if (role == 0) {
                a0 = fmaf(w1r, xs[0][i], bias);
                a1 = fmaf(w1r, xs[1][i], bias);
                a2 = fmaf(w1r, xs[2][i], bias);
                a3 = fmaf(w1r, xs[3][i], bias);
            } else {
                a0 = a1 = a2 = a3 = (role == 1) ? bias : 0.f;
            }
            const float4* src = (role == 2) ? h2s : h1s;
            #pragma unroll
            for (int j = 0; j < HID; ++j) {
                float4 h = src[j];            // broadcast ds_read_b128
                a0 = fmaf(wt[j], h.x, a0);
                a1 = fmaf(wt[j], h.y, a1);
                a2 = fmaf(wt[j], h.z, a2);
                a3 = fmaf(wt[j], h.w, a3);
            }
            if (role == 0) {
                float s;
                s = sigmoid_f(sc * a0); g1a[0][r] = is_cand ? fmaf(2.f, s, -1.f) : s;
                s = sigmoid_f(sc * a1); g1a[1][r] = is_cand ? fmaf(2.f, s, -1.f) : s;
                s = sigmoid_f(sc * a2); g1a[2][r] = is_cand ? fmaf(2.f, s, -1.f) : s;
                s = sigmoid_f(sc * a3); g1a[3][r] = is_cand ? fmaf(2.f, s, -1.f) : s;
            } else if (role == 1) {
                dW0 = a0; dW1 = a1; dW2 = a2; dW3 = a3;
            } else {
                pr2[r] = float4{a0, a1, a2, a3};
            }
        }
        __syncthreads();   // bar1: g1a(i), pr2 ready
        // ---------- phase M ----------
        if (role == 1 && act) {              // finish gates2(i-1)
            float4 p = pr2[r];
            float s;
            s = sigmoid_f(sc * (dW0 + p.x)); g2a[0][r] = is_cand ? fmaf(2.f, s, -1.f) : s;
            s = sigmoid_f(sc * (dW1 + p.y)); g2a[1][r] = is_cand ? fmaf(2.f, s, -1.f) : s;
            s = sigmoid_f(sc * (dW2 + p.z)); g2a[2][r] = is_cand ? fmaf(2.f, s, -1.f) : s;
            s = sigmoid_f(sc * (dW3 + p.w)); g2a[3][r] = is_cand ? fmaf(2.f, s, -1.f) : s;
        }
        if (role == 0 && i < SEQ_L && act) { // update1(i); wave g = batch column
            float gi = g1a[g][l];
            float gf = g1a[g][HID + l];
            float gc = g1a[g][2 * HID + l];
            float go = g1a[g][3 * HID + l];
            c1 = fmaf(gf, c1, gi * gc);
            h1p[l * 4 + g] = go * fmaf(2.f, sigmoid_f(2.f * c1), -1.f);
        }
        __syncthreads();   // bar2: g2a(i-1), h1(i) ready
        // ---------- phase Y: update2(i-1) + output (role2; wave g = batch col)
        if (role == 2 && t2 >= 0) {
            float part = 0.f;
            if (act) {
                float gi = g2a[g][l];
                float gf = g2a[g][HID + l];
                float gc = g2a[g][2 * HID + l];
                float go = g2a[g][3 * HID + l];
                c2 = fmaf(gf, c2, gi * gc);
                float h2v = go * fmaf(2.f, sigmoid_f(2.f * c2), -1.f);
                h2p[l * 4 + g] = h2v;
                part = woutr * h2v;
            }
            #pragma unroll
            for (int off = 32; off > 0; off >>= 1)
                part += __shfl_down(part, off, 64);
            if (l == 0) out[(n0 + g) * SEQ_L + t2] = part + bout;
        }
        __syncthreads();   // bar3: h2(i-1) published before next X reads it
    }
}

extern "C" void kernel_launch(void* const* d_in, const int* in_sizes, int n_in,
                              void* d_out, int out_size, void* d_ws, size_t ws_size,
                              hipStream_t stream)
{
    const float* input = (const float*)d_in[0];
    const float* W1    = (const float*)d_in[1];
    const float* b1    = (const float*)d_in[2];
    const float* R1    = (const float*)d_in[3];
    const float* W2    = (const float*)d_in[4];
    const float* b2    = (const float*)d_in[5];
    const float* R2    = (const float*)d_in[6];
    const float* w_out = (const float*)d_in[7];
    const float* b_out = (const float*)d_in[8];
    float* out = (float*)d_out;

    dim3 grid(1024 / NB);
    dim3 block(NTH);
    hipLaunchKernelGGL(lstm2_kernel, grid, block, 0, stream,
                       input, W1, b1, R1, W2, b2, R2, w_out, b_out, out);
}

// Round 13
// 2362.082 us; speedup vs baseline: 1.5263x; 1.5263x over previous
//
#include <hip/hip_runtime.h>

#define SEQ_L 1000
#define HID   51
#define NB    4      // batches per block; grid = 1024/4 = 256 = 1 block/CU
#define NTH   768    // 12 waves: wave = m*4+ug, m in {R1,W2,R2}, ug = unit-group
#define UPAD  52     // padded unit count for h vectors (unit 51 stays 0)
#define GSTR  20     // dwords per unit in gate buffers: 4 gates * 4 batch + 4 pad

__device__ __forceinline__ float sigmoid_f(float x) {
    return 1.0f / (1.0f + __expf(-x));
}

__global__ __launch_bounds__(NTH, 3)
void lstm2_kernel(const float* __restrict__ input,
                  const float* __restrict__ W1, const float* __restrict__ b1,
                  const float* __restrict__ R1, const float* __restrict__ W2,
                  const float* __restrict__ b2, const float* __restrict__ R2,
                  const float* __restrict__ w_out, const float* __restrict__ b_out,
                  float* __restrict__ out)
{
    const int tid  = threadIdx.x;
    const int n0   = blockIdx.x * NB;
    const int wave = tid >> 6;
    const int lane = tid & 63;
    const int m    = wave >> 2;        // 0: R1(cell1)  1: W2  2: R2
    const int ug   = wave & 3;         // unit group (16 units each)
    const int jq   = lane >> 4;        // j-quarter 0..3
    const int u    = lane & 15;
    const int unit = ug * 16 + u;      // 0..63, valid < 51
    const bool uok = (unit < HID);

    __shared__ float4 h1s[UPAD];             // h1 [unit] x 4 batches
    __shared__ float4 h2s[UPAD];             // h2
    __shared__ float  gl1[64 * GSTR];        // activated cell-1 gates [unit][gate][batch]
    __shared__ float  w2r[64 * GSTR];        // raw W2*h1 partial
    __shared__ float  r2r[64 * GSTR];        // raw R2*h2 partial
    __shared__ float  xs[NB][SEQ_L + 2];     // staged input, +2 zero pad
    __shared__ float  outp[2][4][4];         // out partials [step&1][ug][batch]

    for (int idx = tid; idx < NB * (SEQ_L + 2); idx += NTH) {
        int b = idx / (SEQ_L + 2);
        int t = idx - b * (SEQ_L + 2);
        xs[b][t] = (t < SEQ_L) ? input[(n0 + b) * SEQ_L + t] : 0.f;
    }
    if (tid < UPAD) {
        h1s[tid] = float4{0.f, 0.f, 0.f, 0.f};
        h2s[tid] = float4{0.f, 0.f, 0.f, 0.f};
    }

    // ---- weights: 52 f32/thread (4 gate-rows x 13 j's), statically indexed
    const float* Wm = (m == 0) ? R1 : (m == 1) ? W2 : R2;
    float wt[4][13];
    #pragma unroll
    for (int g = 0; g < 4; ++g)
        #pragma unroll
        for (int jj = 0; jj < 13; ++jj) {
            int j = jq * 13 + jj;
            wt[g][jj] = (uok && j < HID) ? Wm[(g * HID + unit) * HID + j] : 0.f;
        }
    float w1v[4], bv[4];
    #pragma unroll
    for (int g = 0; g < 4; ++g) {
        w1v[g] = (m == 0 && uok) ? W1[g * HID + unit] : 0.f;
        bv[g]  = (uok && m == 0) ? b1[g * HID + unit]
               : (uok && m == 1) ? b2[g * HID + unit] : 0.f;
    }

    // ---- update-role constants (waves 0-3: update1; 4-7: update2; 8: out)
    const int ub  = lane >> 4;         // batch column for update roles
    const int un  = ug * 16 + u;
    float c1 = 0.f, c2 = 0.f;
    const float woutv = (un < HID) ? w_out[un] : 0.f;
    const float bout  = b_out[0];
    float* h1p = (float*)h1s;
    float* h2p = (float*)h2s;

    __syncthreads();

    for (int i = 0; i <= SEQ_L + 1; ++i) {
        // ================= phase X: all 12 waves, blocked matvec ============
        {
            float acc[4][4];
            if (m == 0) {
                float xq0 = xs[0][i], xq1 = xs[1][i], xq2 = xs[2][i], xq3 = xs[3][i];
                #pragma unroll
                for (int g = 0; g < 4; ++g) {
                    acc[g][0] = (jq == 0) ? fmaf(w1v[g], xq0, bv[g]) : 0.f;
                    acc[g][1] = (jq == 0) ? fmaf(w1v[g], xq1, bv[g]) : 0.f;
                    acc[g][2] = (jq == 0) ? fmaf(w1v[g], xq2, bv[g]) : 0.f;
                    acc[g][3] = (jq == 0) ? fmaf(w1v[g], xq3, bv[g]) : 0.f;
                }
            } else {
                #pragma unroll
                for (int g = 0; g < 4; ++g)
                    #pragma unroll
                    for (int b = 0; b < 4; ++b)
                        acc[g][b] = (jq == 0) ? bv[g] : 0.f;   // bv=0 for m==2
            }
            const float4* hsrc = (m == 2) ? h2s : h1s;
            const float4* hq = hsrc + jq * 13;
            #pragma unroll
            for (int jj = 0; jj < 13; ++jj) {
                float4 h = hq[jj];               // b128, 4 distinct addrs/wave
                #pragma unroll
                for (int g = 0; g < 4; ++g) {
                    acc[g][0] = fmaf(wt[g][jj], h.x, acc[g][0]);
                    acc[g][1] = fmaf(wt[g][jj], h.y, acc[g][1]);
                    acc[g][2] = fmaf(wt[g][jj], h.z, acc[g][2]);
                    acc[g][3] = fmaf(wt[g][jj], h.w, acc[g][3]);
                }
            }
            // ---- butterfly reduction over jq via __shfl_xor (known-good
            // primitive; replaces r9's unverified permlane-swap asm).
            // stage 1 (partner jq^1): keep gates {jq&1, (jq&1)+2}
            const bool o1 = (jq & 1);
            const bool o2 = (jq & 2);
            float sA[4], sB[4];
            #pragma unroll
            for (int b = 0; b < 4; ++b) {
                float give01 = o1 ? acc[0][b] : acc[1][b];  // partner's kept gate
                float mine01 = o1 ? acc[1][b] : acc[0][b];  // my kept gate
                sA[b] = mine01 + __shfl_xor(give01, 16, 64);   // gate (jq&1)
                float give23 = o1 ? acc[2][b] : acc[3][b];
                float mine23 = o1 ? acc[3][b] : acc[2][b];
                sB[b] = mine23 + __shfl_xor(give23, 16, 64);   // gate (jq&1)+2
            }
            // stage 2 (partner jq^2): keep gate jq
            float tot[4];
            #pragma unroll
            for (int b = 0; b < 4; ++b) {
                float give2 = o2 ? sA[b] : sB[b];
                float mine2 = o2 ? sB[b] : sA[b];
                tot[b] = mine2 + __shfl_xor(give2, 32, 64);
            }
            float4 wv;
            if (m == 0) {                         // activate cell-1 gates here
                const bool cand = (jq == 2);
                const float sc = cand ? 2.f : 1.f;
                #pragma unroll
                for (int b = 0; b < 4; ++b) {
                    float s = sigmoid_f(sc * tot[b]);
                    (&wv.x)[b] = cand ? fmaf(2.f, s, -1.f) : s;
                }
            } else {
                wv = float4{tot[0], tot[1], tot[2], tot[3]};
            }
            float* gbuf = (m == 0) ? gl1 : (m == 1) ? w2r : r2r;
            if (uok)
                *(float4*)&gbuf[unit * GSTR + jq * 4] = wv;  // one b128/wave
        }
        __syncthreads();   // bar1: gates/partials(i) ready; X h-readers done
        // ================= phase Y: updates + output =======================
        if (wave < 4) {                    // ---- update1(i) -> h1s
            if (i < SEQ_L && un < HID) {
                float gi = gl1[un * GSTR + 0 * 4 + ub];
                float gf = gl1[un * GSTR + 1 * 4 + ub];
                float gc = gl1[un * GSTR + 2 * 4 + ub];
                float go = gl1[un * GSTR + 3 * 4 + ub];
                c1 = fmaf(gf, c1, gi * gc);
                float th = fmaf(2.f, sigmoid_f(2.f * c1), -1.f);
                h1p[un * 4 + ub] = go * th;
            }
        } else if (wave < 8) {             // ---- update2(i-1) -> h2s + out partial
            if (i >= 1 && i <= SEQ_L) {
                float po = 0.f;
                if (un < HID) {
                    float a0 = w2r[un * GSTR + 0 * 4 + ub] + r2r[un * GSTR + 0 * 4 + ub];
                    float a1 = w2r[un * GSTR + 1 * 4 + ub] + r2r[un * GSTR + 1 * 4 + ub];
                    float a2 = w2r[un * GSTR + 2 * 4 + ub] + r2r[un * GSTR + 2 * 4 + ub];
                    float a3 = w2r[un * GSTR + 3 * 4 + ub] + r2r[un * GSTR + 3 * 4 + ub];
                    float gi = sigmoid_f(a0);
                    float gf = sigmoid_f(a1);
                    float gc = fmaf(2.f, sigmoid_f(2.f * a2), -1.f);
                    float go = sigmoid_f(a3);
                    c2 = fmaf(gf, c2, gi * gc);
                    float h2v = go * fmaf(2.f, sigmoid_f(2.f * c2), -1.f);
                    h2p[un * 4 + ub] = h2v;
                    po = woutv * h2v;
                }
                po += __shfl_xor(po, 1, 64);   // reduce over 16 units in-group
                po += __shfl_xor(po, 2, 64);
                po += __shfl_xor(po, 4, 64);
                po += __shfl_xor(po, 8, 64);
                if (u == 0) outp[i & 1][ug][ub] = po;
            }
        } else if (wave == 8) {            // ---- finalize out(i-2)
            if (i >= 2 && lane < 16) {
                int b = lane & 3, q = lane >> 2;
                float v = outp[(i - 1) & 1][q][b];
                v += __shfl_xor(v, 4, 64);
                v += __shfl_xor(v, 8, 64);
                if (q == 0) out[(n0 + b) * SEQ_L + (i - 2)] = v + bout;
            }
        }
        __syncthreads();   // bar2: h1(i)/h2(i-1) published for next X
    }
}

extern "C" void kernel_launch(void* const* d_in, const int* in_sizes, int n_in,
                              void* d_out, int out_size, void* d_ws, size_t ws_size,
                              hipStream_t stream)
{
    const float* input = (const float*)d_in[0];
    const float* W1    = (const float*)d_in[1];
    const float* b1    = (const float*)d_in[2];
    const float* R1    = (const float*)d_in[3];
    const float* W2    = (const float*)d_in[4];
    const float* b2    = (const float*)d_in[5];
    const float* R2    = (const float*)d_in[6];
    const float* w_out = (const float*)d_in[7];
    const float* b_out = (const float*)d_in[8];
    float* out = (float*)d_out;

    dim3 grid(1024 / NB);
    dim3 block(NTH);
    hipLaunchKernelGGL(lstm2_kernel, grid, block, 0, stream,
                       input, W1, b1, R1, W2, b2, R2, w_out, b_out, out);
}